// Round 15
// baseline (329.220 us; speedup 1.0000x reference)
//
#include <hip/hip_runtime.h>
#include <hip/hip_bf16.h>

// ---------------- constants ----------------
constexpr int HH   = 180;
constexpr int WW   = 360;
constexpr int CC   = 192;
constexpr int WS   = 6;
constexpr int SHIFT= 3;
constexpr int NH   = 6;
constexpr int MLAT = HH / WS;   // 30
constexpr int MLON = WW / WS;   // 60
constexpr int NWIN = MLAT * MLON; // 1800
constexpr int NTOK = WS * WS;   // 36
constexpr int HD   = CC / NH;   // 32
constexpr long M_TOK = (long)NWIN * NTOK;  // 64800
constexpr long M_PAD = 65024;              // 508 * 128
constexpr float SCALE_F = 0.17677669529663687f; // 32^-0.5

typedef unsigned short ushort_t;
using bf16x8 = __attribute__((ext_vector_type(8))) short;
using f32x4  = __attribute__((ext_vector_type(4))) float;

static __device__ inline float b2f(ushort_t u) {
    union { float f; unsigned int i; } v; v.i = ((unsigned int)u) << 16; return v.f;
}
static __device__ inline ushort_t f2b(float f) {
    __hip_bfloat16 h = __float2bfloat16(f);   // HW RNE convert
    return *(ushort_t*)&h;
}
static __device__ inline unsigned int cvtpk(float lo, float hi) {
    unsigned int r;
    asm("v_cvt_pk_bf16_f32 %0, %1, %2" : "=v"(r) : "v"(lo), "v"(hi));
    return r;
}

static __device__ inline void gload_lds16(const ushort_t* g, ushort_t* l) {
    __builtin_amdgcn_global_load_lds(
        (const __attribute__((address_space(1))) unsigned int*)g,
        (__attribute__((address_space(3))) unsigned int*)l, 16, 0, 0);
}

// window-order token t -> original flat position (h*W + w)
static __device__ inline int win_map(int ti) {
    int w = ti / NTOK, n = ti - w * NTOK;
    int mlat = w / MLON, mlon = w - mlat * MLON;
    int sh = mlat * WS + n / WS, sw = mlon * WS + (n % WS);
    int hh = sh + SHIFT; if (hh >= HH) hh -= HH;
    int ww2 = sw + SHIFT; if (ww2 >= WW) ww2 -= WW;
    return hh * WW + ww2;
}

// ---------------- merged weight transpose + bf16 convert (one launch) ----------------
__global__ void transpose_all(const float* __restrict__ qkv_w, const float* __restrict__ proj_w,
                              const float* __restrict__ fc1_w, const float* __restrict__ fc2_w,
                              ushort_t* __restrict__ wqkv, ushort_t* __restrict__ wproj,
                              ushort_t* __restrict__ wfc1, ushort_t* __restrict__ wfc2) {
    int e = blockIdx.x * 256 + threadIdx.x;
    const float* in; ushort_t* out; int K, N;
    if (e < 110592)      { in = qkv_w;  out = wqkv;  K = 192; N = 576; }
    else if (e < 147456) { e -= 110592; in = proj_w; out = wproj; K = 192; N = 192; }
    else if (e < 294912) { e -= 147456; in = fc1_w;  out = wfc1;  K = 192; N = 768; }
    else if (e < 442368) { e -= 294912; in = fc2_w;  out = wfc2;  K = 768; N = 192; }
    else return;
    int n = e / K, k = e - n * K;
    out[e] = f2b(in[(long)k * N + n]);
}

__global__ void zero_bf16(ushort_t* __restrict__ p, int count) {
    int e = blockIdx.x * 256 + threadIdx.x;
    if (e < count) p[e] = 0;
}

// ---------------- bias+mask precompute: (MLAT, 2, NH, 36, 48) fp32, pad cols = -1e30 ----------------
static __device__ inline int region1d(int p, int L) {
    return (p < L - WS) ? 0 : ((p < L - SHIFT) ? 1 : 2);
}

__global__ void bias_mask_precompute(const float* __restrict__ bt, float* __restrict__ bm) {
    int idx = blockIdx.x * 256 + threadIdx.x;
    if (idx >= MLAT * 2 * NH * 36 * 48) return;
    int e = idx;
    int j = e % 48; e /= 48;
    int i = e % 36; e /= 36;
    int h = e % NH; e /= NH;
    int lt = e % 2;
    int mlat = e / 2;
    if (j >= 36) { bm[idx] = -1e30f; return; }
    int ih = i / WS, iw = i - ih * WS;
    int jh = j / WS, jw = j - jh * WS;
    int bidx = mlat * 121 + (ih - jh + 5) * 11 + (iw - jw + 5);
    float v = bt[bidx * NH + h];
    int mlon = lt ? (MLON - 1) : 0;
    int ri = region1d(mlat * WS + ih, HH) * 3 + region1d(mlon * WS + iw, WW);
    int rj = region1d(mlat * WS + jh, HH) * 3 + region1d(mlon * WS + jw, WW);
    if (ri != rj) v += -100.0f;
    bm[idx] = v;
}

// ---------------- LN1 + cyclic shift + window partition -> bf16 ----------------
__global__ __launch_bounds__(256) void ln1_window_kernel(
    const float* __restrict__ x, const float* __restrict__ g, const float* __restrict__ b,
    ushort_t* __restrict__ xw)
{
    long t = (long)blockIdx.x * 4 + (threadIdx.x >> 6);
    int lane = threadIdx.x & 63;
    if (t >= M_PAD) return;
    if (t >= M_TOK) {
        ushort_t* o = xw + t * CC;
        o[lane] = 0; o[lane + 64] = 0; o[lane + 128] = 0;
        return;
    }
    int pp = win_map((int)t);
    const float* row = x + (long)pp * CC;
    float v0 = row[lane], v1 = row[lane + 64], v2 = row[lane + 128];
    float s = v0 + v1 + v2;
    float ss = v0 * v0 + v1 * v1 + v2 * v2;
    #pragma unroll
    for (int o = 32; o > 0; o >>= 1) { s += __shfl_xor(s, o, 64); ss += __shfl_xor(ss, o, 64); }
    float mu = s * (1.0f / CC);
    float var = ss * (1.0f / CC) - mu * mu;
    float rinv = rsqrtf(var + 1e-5f);
    ushort_t* o = xw + t * CC;
    o[lane]       = f2b((v0 - mu) * rinv * g[lane]       + b[lane]);
    o[lane + 64]  = f2b((v1 - mu) * rinv * g[lane + 64]  + b[lane + 64]);
    o[lane + 128] = f2b((v2 - mu) * rinv * g[lane + 128] + b[lane + 128]);
}

// ---------------- MFMA GEMM: BM=128, BN=192, BK=64, SINGLE-buffer (occupancy), swizzled ----------------
// LDS 40960 B -> 3-4 blocks/CU; cross-block TLP hides the per-kt stage drains (m97 lesson).
// K-loop LDS rows 128B, byte-in-row swizzled by ((row&7)<<4) -> ds_read_b128 conflict-free.
// MODE 0: outb = bf16(acc + bias) [* SCALE for Q cols] (QKV)    waves 2x4 (64x48)
// MODE 1: outb = bf16(gelu(acc + bias))                (FC1)    waves 2x4 (64x48)
// MODE 2: proj + resid -> outf, fused LN2 -> outb      (proj)   waves 1x8 FULL ROWS (16x192)
// MODE 3: outf[row] += acc + bias                      (FC2)    waves 2x4 (64x48)
#define BM 128
#define BN 192
#define BK 64

template<int MODE, int KK>
__global__ __launch_bounds__(512, (MODE == 2 ? 4 : 6)) void gemm_bf16(
    const ushort_t* __restrict__ A, const ushort_t* __restrict__ Bt,
    const float* __restrict__ bias,
    ushort_t* __restrict__ outb, float* __restrict__ outf,
    const float* __restrict__ resid,
    const float* __restrict__ g2, const float* __restrict__ b2,
    int N, long Mguard, int ncol, int nwg)
{
    constexpr int nt = KK / BK;              // 3 or 12
    constexpr int WMT = (MODE == 2) ? 1 : 4;
    constexpr int WNT = (MODE == 2) ? 12 : 3;
    __shared__ __align__(16) ushort_t lds[20480];   // 40960 B: A 16KB + B 24KB

    int tid = threadIdx.x;
    int lane = tid & 63;
    int wid = tid >> 6;                      // 0..7
    int lr = lane & 15, lg = lane >> 4;
    int wrow0 = (MODE == 2) ? wid * 16 : (wid >> 2) * 64;
    int wcol0 = (MODE == 2) ? 0 : (wid & 3) * 48;

    int orig = blockIdx.x;
    int q = nwg >> 3, r8 = nwg & 7;
    int xcd = orig & 7, pos = orig >> 3;
    int wg = (xcd < r8 ? xcd * (q + 1) : r8 * (q + 1) + (xcd - r8) * q) + pos;
    int brow = wg / ncol, bcol = wg - brow * ncol;
    long bm0 = (long)brow * BM;
    int n0 = bcol * BN;

#define STAGE(k0) do { \
    _Pragma("unroll") \
    for (int i = 0; i < 5; ++i) { \
        int abs_b = tid * 16 + i * 8192; \
        int isA = abs_b < 16384; \
        int loc = isA ? abs_b : abs_b - 16384; \
        int row = loc >> 7, cb = loc & 127; \
        int scol = (cb ^ ((row & 7) << 4)) >> 1; \
        const ushort_t* src = isA ? &A[(bm0 + row) * KK + (k0) + scol] \
                                  : &Bt[(long)(n0 + row) * KK + (k0) + scol]; \
        gload_lds16(src, (ushort_t*)((char*)lds + abs_b)); \
    } \
} while (0)

    f32x4 acc[WMT][WNT] = {};
    int xr = (lr & 7) << 4;   // row&7 == lr&7 for all fragment rows (bases are multiples of 8)

    #pragma unroll
    for (int kt = 0; kt < nt; ++kt) {
        STAGE(kt * BK);
        asm volatile("s_waitcnt vmcnt(0)" ::: "memory");
        __builtin_amdgcn_s_barrier();

        __builtin_amdgcn_s_setprio(1);
        #pragma unroll
        for (int s = 0; s < 2; ++s) {
            bf16x8 af[WMT], bfr[WNT];
            #pragma unroll
            for (int fm = 0; fm < WMT; ++fm) {
                int row = wrow0 + fm * 16 + lr;
                af[fm] = *(const bf16x8*)((const char*)lds + row * 128 + ((s * 64 + lg * 16) ^ xr));
            }
            #pragma unroll
            for (int fn = 0; fn < WNT; ++fn) {
                int row = wcol0 + fn * 16 + lr;
                bfr[fn] = *(const bf16x8*)((const char*)lds + 16384 + row * 128 + ((s * 64 + lg * 16) ^ xr));
            }
            #pragma unroll
            for (int fm = 0; fm < WMT; ++fm)
                #pragma unroll
                for (int fn = 0; fn < WNT; ++fn)
                    acc[fm][fn] = __builtin_amdgcn_mfma_f32_16x16x32_bf16(af[fm], bfr[fn], acc[fm][fn], 0, 0, 0);
        }
        __builtin_amdgcn_s_setprio(0);
        asm volatile("s_waitcnt lgkmcnt(0)" ::: "memory");
        __builtin_amdgcn_s_barrier();
    }
#undef STAGE

    // ---- epilogues (staging LDS now dead -> reusable) ----
    if (MODE == 0 || MODE == 1) {
        float bv[3];
        #pragma unroll
        for (int fn = 0; fn < 3; ++fn) bv[fn] = bias[n0 + wcol0 + fn * 16 + lr];
        ushort_t* bb = lds + wid * 896;   // 16 x 56 bf16 per fm (padded stride)
        #pragma unroll
        for (int fm = 0; fm < 4; ++fm) {
            #pragma unroll
            for (int fn = 0; fn < 3; ++fn) {
                #pragma unroll
                for (int r = 0; r < 4; ++r) {
                    float v = acc[fm][fn][r] + bv[fn];
                    if (MODE == 0) {
                        if (n0 == 0) v *= SCALE_F;   // pre-scale Q block
                    }
                    if (MODE == 1) {
                        float e2 = exp2f(v * -2.4556617f);
                        v = v * __builtin_amdgcn_rcpf(1.0f + e2);
                    }
                    bb[(lg * 4 + r) * 56 + fn * 16 + lr] = f2b(v);
                }
            }
            #pragma unroll
            for (int i = 0; i < 2; ++i) {
                int cid = i * 64 + lane;
                if (cid < 96) {
                    int row = cid / 6, c6 = cid - row * 6;
                    uint4 val = *(const uint4*)&bb[row * 56 + c6 * 8];
                    long grow = bm0 + wrow0 + fm * 16 + row;
                    *(uint4*)&outb[grow * (long)N + n0 + wcol0 + c6 * 8] = val;
                }
            }
        }
    } else if (MODE == 3) {
        float bv[3];
        #pragma unroll
        for (int fn = 0; fn < 3; ++fn) bv[fn] = bias[n0 + wcol0 + fn * 16 + lr];
        float* fb = (float*)lds + wid * 832;   // 16 x 52 f32 per fm (padded stride)
        #pragma unroll
        for (int fm = 0; fm < 4; ++fm) {
            #pragma unroll
            for (int fn = 0; fn < 3; ++fn)
                #pragma unroll
                for (int r = 0; r < 4; ++r)
                    fb[(lg * 4 + r) * 52 + fn * 16 + lr] = acc[fm][fn][r] + bv[fn];
            #pragma unroll
            for (int i = 0; i < 3; ++i) {
                int cid = i * 64 + lane;
                int row = cid / 12, c4 = cid - row * 12;
                f32x4 val = *(const f32x4*)&fb[row * 52 + c4 * 4];
                long grow = bm0 + wrow0 + fm * 16 + row;
                int col = wcol0 + c4 * 4;
                if (grow < Mguard) {
                    float* p = &outf[grow * 192 + col];
                    f32x4 old = *(const f32x4*)p;
                    *(f32x4*)p = old + val;
                }
            }
        }
    } else { // MODE 2: proj + residual + fused LN2, full-row waves (16 rows x 192 cols)
        int* row_map = (int*)((char*)lds + 36864); // [128]
        if (tid < BM) {
            long t = bm0 + tid;
            row_map[tid] = (t < M_TOK) ? win_map((int)t) : -1;
        }
        asm volatile("s_waitcnt lgkmcnt(0)" ::: "memory");
        __builtin_amdgcn_s_barrier();

        float bvv[12];
        #pragma unroll
        for (int fn = 0; fn < 12; ++fn) bvv[fn] = bias[fn * 16 + lr];

        // finalize y = acc + bias + resid; in-wave LN2 stats (rows fully wave-owned)
        float mu4[4], rin4[4];
        #pragma unroll
        for (int r = 0; r < 4; ++r) {
            int lrow = wid * 16 + lg * 4 + r;
            int pp = row_map[lrow];
            float s = 0.f, qq = 0.f;
            #pragma unroll
            for (int fn = 0; fn < 12; ++fn) {
                float vv = acc[0][fn][r] + bvv[fn];
                if (pp >= 0) vv += resid[(long)pp * 192 + fn * 16 + lr];
                acc[0][fn][r] = vv;
                s += vv; qq += vv * vv;
            }
            #pragma unroll
            for (int off = 1; off < 16; off <<= 1) {
                s += __shfl_xor(s, off, 64);
                qq += __shfl_xor(qq, off, 64);
            }
            float mu = s * (1.0f / 192.0f);
            float var = qq * (1.0f / 192.0f) - mu * mu;
            mu4[r] = mu;
            rin4[r] = rsqrtf(var + 1e-5f);
        }

        float gv[12], bv2[12];
        #pragma unroll
        for (int fn = 0; fn < 12; ++fn) {
            gv[fn]  = g2[fn * 16 + lr];
            bv2[fn] = b2[fn * 16 + lr];
        }

        char* ws = (char*)lds + wid * 4608;   // per-wave private scratch (16x68 f32 / 16x72 bf16)
        #pragma unroll
        for (int c = 0; c < 3; ++c) {
            float* fbc = (float*)ws;
            #pragma unroll
            for (int fn2 = 0; fn2 < 4; ++fn2) {
                int fn = c * 4 + fn2;
                #pragma unroll
                for (int r = 0; r < 4; ++r)
                    fbc[(lg * 4 + r) * 68 + fn2 * 16 + lr] = acc[0][fn][r];
            }
            #pragma unroll
            for (int i = 0; i < 4; ++i) {
                int cid = i * 64 + lane;
                int row = cid >> 4, c4 = cid & 15;
                int pp = row_map[wid * 16 + row];
                if (pp >= 0) {
                    f32x4 val = *(const f32x4*)&fbc[row * 68 + c4 * 4];
                    *(f32x4*)&outf[(long)pp * 192 + c * 64 + c4 * 4] = val;
                }
            }
            ushort_t* bbc = (ushort_t*)ws;
            #pragma unroll
            for (int fn2 = 0; fn2 < 4; ++fn2) {
                int fn = c * 4 + fn2;
                #pragma unroll
                for (int r = 0; r < 4; ++r) {
                    float v = (acc[0][fn][r] - mu4[r]) * rin4[r] * gv[fn] + bv2[fn];
                    bbc[(lg * 4 + r) * 72 + fn2 * 16 + lr] = f2b(v);
                }
            }
            #pragma unroll
            for (int i = 0; i < 2; ++i) {
                int cid = i * 64 + lane;
                int row = cid >> 3, c8 = cid & 7;
                int pp = row_map[wid * 16 + row];
                if (pp >= 0) {
                    uint4 val = *(const uint4*)&bbc[row * 72 + c8 * 8];
                    *(uint4*)&outb[(long)pp * 192 + c * 64 + c8 * 8] = val;
                }
            }
        }
    }
}

// ---------------- LDS-free MFMA attention: swapped operands, one wave per (window, head) ----------------
__global__ __launch_bounds__(256) void attn_mfma_kernel(
    const ushort_t* __restrict__ qkv,     // M_PAD x 576 bf16, cols [3][NH][HD], Q pre-scaled
    const float* __restrict__ bm,         // (MLAT, 2, NH, 36, 48) fp32 bias+mask
    ushort_t* __restrict__ av)            // M_PAD x 192 bf16
{
    int wid = threadIdx.x >> 6, lane = threadIdx.x & 63;
    int unit = blockIdx.x * 4 + wid;
    int w = unit / NH, h = unit - (unit / NH) * NH;
    int mlat = w / MLON, mlon = w - mlat * MLON;
    int lr = lane & 15, lg = lane >> 4;

    const ushort_t* Qb = qkv + (long)w * NTOK * 576 + h * HD;
    const ushort_t* Kb = Qb + 192;
    const ushort_t* Vb = Qb + 384;

    bf16x8 kf[3], qf[3];
    #pragma unroll
    for (int t = 0; t < 3; ++t) {
        kf[t] = *(const bf16x8*)&Kb[(long)(t * 16 + lr) * 576 + 8 * lg];
        qf[t] = *(const bf16x8*)&Qb[(long)(t * 16 + lr) * 576 + 8 * lg];
    }
    f32x4 st[3][3] = {};   // [mt = kv tile][qt = q tile]
    #pragma unroll
    for (int mt = 0; mt < 3; ++mt)
        #pragma unroll
        for (int qt = 0; qt < 3; ++qt)
            st[mt][qt] = __builtin_amdgcn_mfma_f32_16x16x32_bf16(kf[mt], qf[qt], st[mt][qt], 0, 0, 0);

    bf16x8 vf[2][2];   // [nd = d tile][kt = kv half]
    #pragma unroll
    for (int nd = 0; nd < 2; ++nd)
        #pragma unroll
        for (int kt = 0; kt < 2; ++kt)
            #pragma unroll
            for (int j = 0; j < 8; ++j)
                ((short*)&vf[nd][kt])[j] =
                    (short)Vb[(long)(kt * 32 + 8 * lg + j) * 576 + nd * 16 + lr];

    const float* bb = bm + (((mlat * 2 + (mlon == MLON - 1)) * NH) + h) * (36 * 48);

    f32x4 o[2][3] = {};   // [nd][qt]
    int src0 = ((2 * (lg & 1)) << 4) | lr;
    int src1 = src0 + 16;

    #pragma unroll
    for (int qt = 0; qt < 3; ++qt) {
        int qrow = qt * 16 + lr;
        int qq = qrow < 36 ? qrow : 35;
        float v[3][4];
        #pragma unroll
        for (int mt = 0; mt < 3; ++mt) {
            f32x4 b4 = *(const f32x4*)&bb[qq * 48 + mt * 16 + 4 * lg];
            #pragma unroll
            for (int r = 0; r < 4; ++r) v[mt][r] = st[mt][qt][r] + b4[r];
        }
        float mx = v[0][0];
        #pragma unroll
        for (int mt = 0; mt < 3; ++mt)
            #pragma unroll
            for (int r = 0; r < 4; ++r) mx = fmaxf(mx, v[mt][r]);
        mx = fmaxf(mx, __shfl_xor(mx, 16, 64));
        mx = fmaxf(mx, __shfl_xor(mx, 32, 64));
        float p[3][4], sum = 0.f;
        #pragma unroll
        for (int mt = 0; mt < 3; ++mt)
            #pragma unroll
            for (int r = 0; r < 4; ++r) { p[mt][r] = __expf(v[mt][r] - mx); sum += p[mt][r]; }
        sum += __shfl_xor(sum, 16, 64);
        sum += __shfl_xor(sum, 32, 64);
        float rs = 1.0f / sum;

        unsigned int pk[3][2];
        #pragma unroll
        for (int mt = 0; mt < 3; ++mt) {
            pk[mt][0] = cvtpk(p[mt][0] * rs, p[mt][1] * rs);
            pk[mt][1] = cvtpk(p[mt][2] * rs, p[mt][3] * rs);
        }
        unsigned int f0[4], f1[4];
        {
            unsigned int a, b;
            a = (unsigned)__shfl((int)pk[0][0], src0, 64); b = (unsigned)__shfl((int)pk[1][0], src0, 64);
            f0[0] = (lg < 2) ? a : b;
            a = (unsigned)__shfl((int)pk[0][1], src0, 64); b = (unsigned)__shfl((int)pk[1][1], src0, 64);
            f0[1] = (lg < 2) ? a : b;
            a = (unsigned)__shfl((int)pk[0][0], src1, 64); b = (unsigned)__shfl((int)pk[1][0], src1, 64);
            f0[2] = (lg < 2) ? a : b;
            a = (unsigned)__shfl((int)pk[0][1], src1, 64); b = (unsigned)__shfl((int)pk[1][1], src1, 64);
            f0[3] = (lg < 2) ? a : b;
            f1[0] = (lg < 2) ? (unsigned)__shfl((int)pk[2][0], src0, 64) : 0u;
            f1[1] = (lg < 2) ? (unsigned)__shfl((int)pk[2][1], src0, 64) : 0u;
            f1[2] = (lg < 2) ? (unsigned)__shfl((int)pk[2][0], src1, 64) : 0u;
            f1[3] = (lg < 2) ? (unsigned)__shfl((int)pk[2][1], src1, 64) : 0u;
        }
        union { unsigned int u[4]; bf16x8 v8; } pf0, pf1;
        pf0.u[0] = f0[0]; pf0.u[1] = f0[1]; pf0.u[2] = f0[2]; pf0.u[3] = f0[3];
        pf1.u[0] = f1[0]; pf1.u[1] = f1[1]; pf1.u[2] = f1[2]; pf1.u[3] = f1[3];

        #pragma unroll
        for (int nd = 0; nd < 2; ++nd) {
            o[nd][qt] = __builtin_amdgcn_mfma_f32_16x16x32_bf16(vf[nd][0], pf0.v8, o[nd][qt], 0, 0, 0);
            o[nd][qt] = __builtin_amdgcn_mfma_f32_16x16x32_bf16(vf[nd][1], pf1.v8, o[nd][qt], 0, 0, 0);
        }
    }

    #pragma unroll
    for (int qt = 0; qt < 3; ++qt) {
        int qrow = qt * 16 + lr;
        if (qrow < NTOK) {
            #pragma unroll
            for (int nd = 0; nd < 2; ++nd) {
                uint2 pkd;
                pkd.x = cvtpk(o[nd][qt][0], o[nd][qt][1]);
                pkd.y = cvtpk(o[nd][qt][2], o[nd][qt][3]);
                *(uint2*)&av[((long)w * NTOK + qrow) * CC + h * HD + nd * 16 + 4 * lg] = pkd;
            }
        }
    }
}

// ---------------- launch ----------------
extern "C" void kernel_launch(void* const* d_in, const int* in_sizes, int n_in,
                              void* d_out, int out_size, void* d_ws, size_t ws_size,
                              hipStream_t stream) {
    const float* x        = (const float*)d_in[0];
    const float* n1w      = (const float*)d_in[1];
    const float* n1b      = (const float*)d_in[2];
    const float* qkv_w    = (const float*)d_in[3];
    const float* qkv_b    = (const float*)d_in[4];
    const float* proj_w   = (const float*)d_in[5];
    const float* proj_b   = (const float*)d_in[6];
    const float* btab     = (const float*)d_in[7];
    const float* n2w      = (const float*)d_in[8];
    const float* n2b      = (const float*)d_in[9];
    const float* fc1_w    = (const float*)d_in[10];
    const float* fc1_b    = (const float*)d_in[11];
    const float* fc2_w    = (const float*)d_in[12];
    const float* fc2_b    = (const float*)d_in[13];
    float* out = (float*)d_out;

    char* p = (char*)d_ws;
    ushort_t* xw  = (ushort_t*)p;  p += M_PAD * 192 * 2;
    ushort_t* big = (ushort_t*)p;  p += M_PAD * 768 * 2;
    ushort_t* av  = (ushort_t*)p;  p += M_PAD * 192 * 2;
    ushort_t* wqkv = (ushort_t*)p; p += 576 * 192 * 2;
    ushort_t* wproj= (ushort_t*)p; p += 192 * 192 * 2;
    ushort_t* wfc1 = (ushort_t*)p; p += 768 * 192 * 2;
    ushort_t* wfc2 = (ushort_t*)p; p += 192 * 768 * 2;
    float*    bmask= (float*)p;    p += MLAT * 2 * NH * 36 * 48 * 4;

    transpose_all<<<(442368 + 255)/256, 256, 0, stream>>>(
        qkv_w, proj_w, fc1_w, fc2_w, wqkv, wproj, wfc1, wfc2);
    bias_mask_precompute<<<(MLAT*2*NH*36*48 + 255)/256, 256, 0, stream>>>(btab, bmask);
    zero_bf16<<<((int)(M_PAD - M_TOK)*192 + 255)/256, 256, 0, stream>>>(av + M_TOK * 192, (int)(M_PAD - M_TOK) * 192);

    ln1_window_kernel<<<M_PAD / 4, 256, 0, stream>>>(x, n1w, n1b, xw);

    // QKV: (M_PAD x 192) @ (192 x 576), 3 col-blocks (Q block pre-scaled by SCALE_F)
    gemm_bf16<0, 192><<<508 * 3, 512, 0, stream>>>(
        xw, wqkv, qkv_b, big, nullptr, nullptr, nullptr, nullptr, 576, M_PAD, 3, 508 * 3);

    attn_mfma_kernel<<<NWIN * NH / 4, 256, 0, stream>>>(big, bmask, av);

    // proj + window reverse + residual -> out (fp32), fused LN2 -> xw (bf16)
    gemm_bf16<2, 192><<<508, 512, 0, stream>>>(
        av, wproj, proj_b, xw, out, x, n2w, n2b, 192, M_TOK, 1, 508);

    // FC1 + GELU: (M_PAD x 192) @ (192 x 768), 4 col-blocks
    gemm_bf16<1, 192><<<508 * 4, 512, 0, stream>>>(
        xw, wfc1, fc1_b, big, nullptr, nullptr, nullptr, nullptr, 768, M_PAD, 4, 508 * 4);

    // FC2 + residual accumulate into out, 1 col-block
    gemm_bf16<3, 768><<<508, 512, 0, stream>>>(
        big, wfc2, fc2_b, nullptr, out, nullptr, nullptr, nullptr, 192, M_TOK, 1, 508);
}

// Round 16
// 232.132 us; speedup vs baseline: 1.4182x; 1.4182x over previous
//
#include <hip/hip_runtime.h>
#include <hip/hip_bf16.h>

// ---------------- constants ----------------
constexpr int HH   = 180;
constexpr int WW   = 360;
constexpr int CC   = 192;
constexpr int WS   = 6;
constexpr int SHIFT= 3;
constexpr int NH   = 6;
constexpr int MLAT = HH / WS;   // 30
constexpr int MLON = WW / WS;   // 60
constexpr int NWIN = MLAT * MLON; // 1800
constexpr int NTOK = WS * WS;   // 36
constexpr int HD   = CC / NH;   // 32
constexpr long M_TOK = (long)NWIN * NTOK;  // 64800
constexpr long M_PAD = 65024;              // 508 * 128
constexpr float SCALE_F = 0.17677669529663687f; // 32^-0.5

typedef unsigned short ushort_t;
using bf16x8 = __attribute__((ext_vector_type(8))) short;
using f32x4  = __attribute__((ext_vector_type(4))) float;

static __device__ inline float b2f(ushort_t u) {
    union { float f; unsigned int i; } v; v.i = ((unsigned int)u) << 16; return v.f;
}
static __device__ inline ushort_t f2b(float f) {
    __hip_bfloat16 h = __float2bfloat16(f);   // HW RNE convert
    return *(ushort_t*)&h;
}
static __device__ inline unsigned int cvtpk(float lo, float hi) {
    unsigned int r;
    asm("v_cvt_pk_bf16_f32 %0, %1, %2" : "=v"(r) : "v"(lo), "v"(hi));
    return r;
}

static __device__ inline void gload_lds16(const ushort_t* g, ushort_t* l) {
    __builtin_amdgcn_global_load_lds(
        (const __attribute__((address_space(1))) unsigned int*)g,
        (__attribute__((address_space(3))) unsigned int*)l, 16, 0, 0);
}

// window-order token t -> original flat position (h*W + w)
static __device__ inline int win_map(int ti) {
    int w = ti / NTOK, n = ti - w * NTOK;
    int mlat = w / MLON, mlon = w - mlat * MLON;
    int sh = mlat * WS + n / WS, sw = mlon * WS + (n % WS);
    int hh = sh + SHIFT; if (hh >= HH) hh -= HH;
    int ww2 = sw + SHIFT; if (ww2 >= WW) ww2 -= WW;
    return hh * WW + ww2;
}

// ---------------- merged weight transpose + bf16 convert (one launch) ----------------
__global__ void transpose_all(const float* __restrict__ qkv_w, const float* __restrict__ proj_w,
                              const float* __restrict__ fc1_w, const float* __restrict__ fc2_w,
                              ushort_t* __restrict__ wqkv, ushort_t* __restrict__ wproj,
                              ushort_t* __restrict__ wfc1, ushort_t* __restrict__ wfc2) {
    int e = blockIdx.x * 256 + threadIdx.x;
    const float* in; ushort_t* out; int K, N;
    if (e < 110592)      { in = qkv_w;  out = wqkv;  K = 192; N = 576; }
    else if (e < 147456) { e -= 110592; in = proj_w; out = wproj; K = 192; N = 192; }
    else if (e < 294912) { e -= 147456; in = fc1_w;  out = wfc1;  K = 192; N = 768; }
    else if (e < 442368) { e -= 294912; in = fc2_w;  out = wfc2;  K = 768; N = 192; }
    else return;
    int n = e / K, k = e - n * K;
    out[e] = f2b(in[(long)k * N + n]);
}

__global__ void zero_bf16(ushort_t* __restrict__ p, int count) {
    int e = blockIdx.x * 256 + threadIdx.x;
    if (e < count) p[e] = 0;
}

// ---------------- bias+mask precompute: (MLAT, 2, NH, 36, 48) fp32, pad cols = -1e30 ----------------
static __device__ inline int region1d(int p, int L) {
    return (p < L - WS) ? 0 : ((p < L - SHIFT) ? 1 : 2);
}

__global__ void bias_mask_precompute(const float* __restrict__ bt, float* __restrict__ bm) {
    int idx = blockIdx.x * 256 + threadIdx.x;
    if (idx >= MLAT * 2 * NH * 36 * 48) return;
    int e = idx;
    int j = e % 48; e /= 48;
    int i = e % 36; e /= 36;
    int h = e % NH; e /= NH;
    int lt = e % 2;
    int mlat = e / 2;
    if (j >= 36) { bm[idx] = -1e30f; return; }
    int ih = i / WS, iw = i - ih * WS;
    int jh = j / WS, jw = j - jh * WS;
    int bidx = mlat * 121 + (ih - jh + 5) * 11 + (iw - jw + 5);
    float v = bt[bidx * NH + h];
    int mlon = lt ? (MLON - 1) : 0;
    int ri = region1d(mlat * WS + ih, HH) * 3 + region1d(mlon * WS + iw, WW);
    int rj = region1d(mlat * WS + jh, HH) * 3 + region1d(mlon * WS + jw, WW);
    if (ri != rj) v += -100.0f;
    bm[idx] = v;
}

// ---------------- LN1 + cyclic shift + window partition -> bf16 ----------------
__global__ __launch_bounds__(256) void ln1_window_kernel(
    const float* __restrict__ x, const float* __restrict__ g, const float* __restrict__ b,
    ushort_t* __restrict__ xw)
{
    long t = (long)blockIdx.x * 4 + (threadIdx.x >> 6);
    int lane = threadIdx.x & 63;
    if (t >= M_PAD) return;
    if (t >= M_TOK) {
        ushort_t* o = xw + t * CC;
        o[lane] = 0; o[lane + 64] = 0; o[lane + 128] = 0;
        return;
    }
    int pp = win_map((int)t);
    const float* row = x + (long)pp * CC;
    float v0 = row[lane], v1 = row[lane + 64], v2 = row[lane + 128];
    float s = v0 + v1 + v2;
    float ss = v0 * v0 + v1 * v1 + v2 * v2;
    #pragma unroll
    for (int o = 32; o > 0; o >>= 1) { s += __shfl_xor(s, o, 64); ss += __shfl_xor(ss, o, 64); }
    float mu = s * (1.0f / CC);
    float var = ss * (1.0f / CC) - mu * mu;
    float rinv = rsqrtf(var + 1e-5f);
    ushort_t* o = xw + t * CC;
    o[lane]       = f2b((v0 - mu) * rinv * g[lane]       + b[lane]);
    o[lane + 64]  = f2b((v1 - mu) * rinv * g[lane + 64]  + b[lane + 64]);
    o[lane + 128] = f2b((v2 - mu) * rinv * g[lane + 128] + b[lane + 128]);
}

// ---------------- MFMA GEMM (QKV / proj+LN2): BM=128, BN=192, BK=64, dbuf, swizzled, 8 waves ----------------
// MODE 0: outb = bf16(acc + bias) [* SCALE for Q cols] (QKV)
// MODE 2: proj + window-reverse + residual -> outf, AND fused LN2 -> outb (xw)
#define BM 128
#define BN 192
#define BK 64

template<int MODE, int KK>
__global__ __launch_bounds__(512, 4) void gemm_bf16(
    const ushort_t* __restrict__ A, const ushort_t* __restrict__ Bt,
    const float* __restrict__ bias,
    ushort_t* __restrict__ outb, float* __restrict__ outf,
    const float* __restrict__ resid,
    const float* __restrict__ g2, const float* __restrict__ b2,
    int N, long Mguard, int ncol, int nwg)
{
    constexpr int nt = KK / BK;              // 3
    __shared__ __align__(16) ushort_t lds[40960];   // dbuf 2x40960 B

    int tid = threadIdx.x;
    int lane = tid & 63;
    int wid = tid >> 6;
    int lr = lane & 15, lg = lane >> 4;
    int wm = wid >> 2, wn = wid & 3;

    int orig = blockIdx.x;
    int q = nwg >> 3, r8 = nwg & 7;
    int xcd = orig & 7, pos = orig >> 3;
    int wg = (xcd < r8 ? xcd * (q + 1) : r8 * (q + 1) + (xcd - r8) * q) + pos;
    int brow = wg / ncol, bcol = wg - brow * ncol;
    long bm0 = (long)brow * BM;
    int n0 = bcol * BN;

#define STAGE(b, k0) do { \
    char* base = (char*)lds + (b) * 40960; \
    _Pragma("unroll") \
    for (int i = 0; i < 5; ++i) { \
        int abs_b = tid * 16 + i * 8192; \
        int isA = abs_b < 16384; \
        int loc = isA ? abs_b : abs_b - 16384; \
        int row = loc >> 7, cb = loc & 127; \
        int scol = (cb ^ ((row & 7) << 4)) >> 1; \
        const ushort_t* src = isA ? &A[(bm0 + row) * KK + (k0) + scol] \
                                  : &Bt[(long)(n0 + row) * KK + (k0) + scol]; \
        gload_lds16(src, (ushort_t*)(base + abs_b)); \
    } \
} while (0)

    f32x4 acc[4][3] = {};

    STAGE(0, 0);
    asm volatile("s_waitcnt vmcnt(0)" ::: "memory");
    __builtin_amdgcn_s_barrier();

    int xr = (lr & 7) << 4;

    #pragma unroll
    for (int kt = 0; kt < nt; ++kt) {
        if (kt + 1 < nt) {
            STAGE((kt + 1) & 1, (kt + 1) * BK);
            asm volatile("s_waitcnt vmcnt(5)" ::: "memory");
        } else {
            asm volatile("s_waitcnt vmcnt(0)" ::: "memory");
        }
        __builtin_amdgcn_s_barrier();

        const char* base = (const char*)lds + (kt & 1) * 40960;
        __builtin_amdgcn_s_setprio(1);
        #pragma unroll
        for (int s = 0; s < 2; ++s) {
            bf16x8 af[4], bfr[3];
            #pragma unroll
            for (int fm = 0; fm < 4; ++fm) {
                int row = wm * 64 + fm * 16 + lr;
                af[fm] = *(const bf16x8*)(base + row * 128 + ((s * 64 + lg * 16) ^ xr));
            }
            #pragma unroll
            for (int fn = 0; fn < 3; ++fn) {
                int row = wn * 48 + fn * 16 + lr;
                bfr[fn] = *(const bf16x8*)(base + 16384 + row * 128 + ((s * 64 + lg * 16) ^ xr));
            }
            #pragma unroll
            for (int fm = 0; fm < 4; ++fm)
                #pragma unroll
                for (int fn = 0; fn < 3; ++fn)
                    acc[fm][fn] = __builtin_amdgcn_mfma_f32_16x16x32_bf16(af[fm], bfr[fn], acc[fm][fn], 0, 0, 0);
        }
        __builtin_amdgcn_s_setprio(0);
        asm volatile("s_waitcnt lgkmcnt(0)" ::: "memory");
        __builtin_amdgcn_s_barrier();
    }
#undef STAGE

    float bv[3];
    #pragma unroll
    for (int fn = 0; fn < 3; ++fn) bv[fn] = bias[n0 + wn * 48 + fn * 16 + lr];

    if (MODE == 0) {
        ushort_t* bb = lds + wid * 896;   // 16 x 56 bf16 per fm (padded stride)
        #pragma unroll
        for (int fm = 0; fm < 4; ++fm) {
            #pragma unroll
            for (int fn = 0; fn < 3; ++fn) {
                #pragma unroll
                for (int r = 0; r < 4; ++r) {
                    float v = acc[fm][fn][r] + bv[fn];
                    if (n0 == 0) v *= SCALE_F;   // pre-scale Q block
                    bb[(lg * 4 + r) * 56 + fn * 16 + lr] = f2b(v);
                }
            }
            #pragma unroll
            for (int i = 0; i < 2; ++i) {
                int cid = i * 64 + lane;
                if (cid < 96) {
                    int row = cid / 6, c6 = cid - row * 6;
                    uint4 val = *(const uint4*)&bb[row * 56 + c6 * 8];
                    long grow = bm0 + wm * 64 + fm * 16 + row;
                    *(uint4*)&outb[grow * (long)N + n0 + wn * 48 + c6 * 8] = val;
                }
            }
        }
    } else { // MODE 2: proj + residual + fused LN2
        float* redS = (float*)((char*)lds + 73728);  // [128][4]
        float* redQ = (float*)((char*)lds + 75776);  // [128][4]
        int*   row_map = (int*)((char*)lds + 78336); // [128]
        if (tid < BM) {
            long t = bm0 + tid;
            row_map[tid] = (t < M_TOK) ? win_map((int)t) : -1;
        }
        asm volatile("s_waitcnt lgkmcnt(0)" ::: "memory");
        __builtin_amdgcn_s_barrier();

        #pragma unroll
        for (int fm = 0; fm < 4; ++fm) {
            float s4[4], q4[4];
            #pragma unroll
            for (int r = 0; r < 4; ++r) {
                int lrow = wm * 64 + fm * 16 + lg * 4 + r;
                int pp = row_map[lrow];
                float s = 0.f, qq = 0.f;
                #pragma unroll
                for (int fn = 0; fn < 3; ++fn) {
                    float vv = acc[fm][fn][r] + bv[fn];
                    if (pp >= 0) vv += resid[(long)pp * 192 + wn * 48 + fn * 16 + lr];
                    acc[fm][fn][r] = vv;
                    s += vv; qq += vv * vv;
                }
                s4[r] = s; q4[r] = qq;
            }
            #pragma unroll
            for (int off = 1; off < 16; off <<= 1)
                #pragma unroll
                for (int r = 0; r < 4; ++r) {
                    s4[r] += __shfl_xor(s4[r], off, 64);
                    q4[r] += __shfl_xor(q4[r], off, 64);
                }
            if (lr == 0) {
                #pragma unroll
                for (int r = 0; r < 4; ++r) {
                    int row = wm * 64 + fm * 16 + lg * 4 + r;
                    redS[row * 4 + wn] = s4[r];
                    redQ[row * 4 + wn] = q4[r];
                }
            }
        }
        asm volatile("s_waitcnt lgkmcnt(0)" ::: "memory");
        __builtin_amdgcn_s_barrier();

        float gv[3], bv2[3];
        #pragma unroll
        for (int fn = 0; fn < 3; ++fn) {
            gv[fn]  = g2[wn * 48 + fn * 16 + lr];
            bv2[fn] = b2[wn * 48 + fn * 16 + lr];
        }

        float* fb = (float*)lds + wid * 832;
        ushort_t* bb = (ushort_t*)((char*)lds + 32768) + wid * 896;
        #pragma unroll
        for (int fm = 0; fm < 4; ++fm) {
            float mu4[4], rin4[4];
            #pragma unroll
            for (int r = 0; r < 4; ++r) {
                int row = wm * 64 + fm * 16 + lg * 4 + r;
                float s = redS[row * 4 + 0] + redS[row * 4 + 1] + redS[row * 4 + 2] + redS[row * 4 + 3];
                float qq = redQ[row * 4 + 0] + redQ[row * 4 + 1] + redQ[row * 4 + 2] + redQ[row * 4 + 3];
                float mu = s * (1.0f / 192.0f);
                float var = qq * (1.0f / 192.0f) - mu * mu;
                mu4[r] = mu;
                rin4[r] = rsqrtf(var + 1e-5f);
            }
            #pragma unroll
            for (int fn = 0; fn < 3; ++fn)
                #pragma unroll
                for (int r = 0; r < 4; ++r) {
                    float vv = acc[fm][fn][r];
                    fb[(lg * 4 + r) * 52 + fn * 16 + lr] = vv;
                    bb[(lg * 4 + r) * 56 + fn * 16 + lr] =
                        f2b((vv - mu4[r]) * rin4[r] * gv[fn] + bv2[fn]);
                }
            #pragma unroll
            for (int i = 0; i < 3; ++i) {
                int cid = i * 64 + lane;
                int row = cid / 12, c4 = cid - row * 12;
                int pp = row_map[wm * 64 + fm * 16 + row];
                if (pp >= 0) {
                    f32x4 val = *(const f32x4*)&fb[row * 52 + c4 * 4];
                    *(f32x4*)&outf[(long)pp * 192 + wn * 48 + c4 * 4] = val;
                }
            }
            #pragma unroll
            for (int i = 0; i < 2; ++i) {
                int cid = i * 64 + lane;
                if (cid < 96) {
                    int row = cid / 6, c6 = cid - row * 6;
                    int pp = row_map[wm * 64 + fm * 16 + row];
                    if (pp >= 0) {
                        uint4 val = *(const uint4*)&bb[row * 56 + c6 * 8];
                        *(uint4*)&outb[(long)pp * 192 + wn * 48 + c6 * 8] = val;
                    }
                }
            }
        }
    }
}

// ---------------- fused MLP: out[rows] += fc2(gelu(fc1(xw))) , 128 rows/block ----------------
// R1 (32 KB): A+W1 staging (phase A) / W2 staging (phase C) / epilogue bounce.
// H  (34816 B @ 32768): 128 x 136-ushort rows (272 B, 17x16B -> 2-way-free b128 reads).
__global__ __launch_bounds__(512, 4) void fused_mlp(
    const ushort_t* __restrict__ xw, const ushort_t* __restrict__ w1,
    const float* __restrict__ b1, const ushort_t* __restrict__ w2,
    const float* __restrict__ b2v, float* __restrict__ outf, int nwg)
{
    __shared__ __align__(16) ushort_t lds[33792];   // 67584 B total
    int tid = threadIdx.x;
    int lane = tid & 63;
    int wid = tid >> 6;
    int lr = lane & 15, lg = lane >> 4;
    int wm = wid >> 2;      // 0..1: row group (64 rows)
    int wc2 = wid & 3;      // col group

    int orig = blockIdx.x;
    int q = nwg >> 3, r8 = nwg & 7;
    int xcd = orig & 7, pos = orig >> 3;
    int wg = (xcd < r8 ? xcd * (q + 1) : r8 * (q + 1) + (xcd - r8) * q) + pos;
    long bm0 = (long)wg * 128;

    int xr = (lr & 7) << 4;
    char* R1 = (char*)lds;
    char* Hb = (char*)lds + 32768;
    ushort_t* Hu = (ushort_t*)Hb;

#define STAGE_W2(sub) do { \
    _Pragma("unroll") \
    for (int i = 0; i < 3; ++i) { \
        int abs_b = tid * 16 + i * 8192; \
        int row = abs_b >> 7, cb = abs_b & 127; \
        int scol = (cb ^ ((row & 7) << 4)) >> 1; \
        gload_lds16(&w2[(long)row * 768 + ch * 128 + (sub) * 64 + scol], \
                    (ushort_t*)(R1 + abs_b)); \
    } \
} while (0)

#define C_COMPUTE(sub) do { \
    __builtin_amdgcn_s_setprio(1); \
    _Pragma("unroll") \
    for (int s = 0; s < 2; ++s) { \
        bf16x8 af2[4], bf2[3]; \
        _Pragma("unroll") \
        for (int fm = 0; fm < 4; ++fm) { \
            int row = wm * 64 + fm * 16 + lr; \
            af2[fm] = *(const bf16x8*)(Hb + row * 272 + (sub) * 128 + s * 64 + lg * 16); \
        } \
        _Pragma("unroll") \
        for (int fn = 0; fn < 3; ++fn) { \
            int row = wc2 * 48 + fn * 16 + lr; \
            bf2[fn] = *(const bf16x8*)(R1 + row * 128 + ((s * 64 + lg * 16) ^ xr)); \
        } \
        _Pragma("unroll") \
        for (int fm = 0; fm < 4; ++fm) \
            _Pragma("unroll") \
            for (int fn = 0; fn < 3; ++fn) \
                acc2[fm][fn] = __builtin_amdgcn_mfma_f32_16x16x32_bf16(af2[fm], bf2[fn], acc2[fm][fn], 0, 0, 0); \
    } \
    __builtin_amdgcn_s_setprio(0); \
} while (0)

    f32x4 acc2[4][3] = {};

    #pragma unroll 1
    for (int ch = 0; ch < 6; ++ch) {
        // ---- phase A: acc1 = xw(128x192) @ w1chunk(128h x 192)^T ----
        f32x4 acc1[4][2] = {};
        #pragma unroll
        for (int kt = 0; kt < 3; ++kt) {
            #pragma unroll
            for (int i = 0; i < 4; ++i) {
                int abs_b = tid * 16 + i * 8192;
                int isA = abs_b < 16384;
                int loc = isA ? abs_b : abs_b - 16384;
                int row = loc >> 7, cb = loc & 127;
                int scol = (cb ^ ((row & 7) << 4)) >> 1;
                const ushort_t* src = isA ? &xw[(bm0 + row) * 192 + kt * 64 + scol]
                                          : &w1[(long)(ch * 128 + row) * 192 + kt * 64 + scol];
                gload_lds16(src, (ushort_t*)(R1 + abs_b));
            }
            asm volatile("s_waitcnt vmcnt(0)" ::: "memory");
            __builtin_amdgcn_s_barrier();
            __builtin_amdgcn_s_setprio(1);
            #pragma unroll
            for (int s = 0; s < 2; ++s) {
                bf16x8 af[4], bf1[2];
                #pragma unroll
                for (int fm = 0; fm < 4; ++fm) {
                    int row = wm * 64 + fm * 16 + lr;
                    af[fm] = *(const bf16x8*)(R1 + row * 128 + ((s * 64 + lg * 16) ^ xr));
                }
                #pragma unroll
                for (int fn = 0; fn < 2; ++fn) {
                    int row = wc2 * 32 + fn * 16 + lr;
                    bf1[fn] = *(const bf16x8*)(R1 + 16384 + row * 128 + ((s * 64 + lg * 16) ^ xr));
                }
                #pragma unroll
                for (int fm = 0; fm < 4; ++fm)
                    #pragma unroll
                    for (int fn = 0; fn < 2; ++fn)
                        acc1[fm][fn] = __builtin_amdgcn_mfma_f32_16x16x32_bf16(af[fm], bf1[fn], acc1[fm][fn], 0, 0, 0);
            }
            __builtin_amdgcn_s_setprio(0);
            asm volatile("s_waitcnt lgkmcnt(0)" ::: "memory");
            __builtin_amdgcn_s_barrier();
        }

        // pre-issue W2 sub0 staging into R1 (free now); latency hides under phase B
        STAGE_W2(0);

        // ---- phase B: H = gelu(acc1 + b1) -> Hb ----
        float bv1a = b1[ch * 128 + wc2 * 32 + lr];
        float bv1b = b1[ch * 128 + wc2 * 32 + 16 + lr];
        #pragma unroll
        for (int fm = 0; fm < 4; ++fm)
            #pragma unroll
            for (int fn = 0; fn < 2; ++fn)
                #pragma unroll
                for (int r = 0; r < 4; ++r) {
                    float v = acc1[fm][fn][r] + (fn ? bv1b : bv1a);
                    float e2 = exp2f(v * -2.4556617f);
                    v = v * __builtin_amdgcn_rcpf(1.0f + e2);
                    Hu[(wm * 64 + fm * 16 + lg * 4 + r) * 136 + wc2 * 32 + fn * 16 + lr] = f2b(v);
                }
        asm volatile("s_waitcnt vmcnt(0) lgkmcnt(0)" ::: "memory");
        __builtin_amdgcn_s_barrier();

        // ---- phase C: acc2 += H(128x128) @ w2chunk, two 64-k sub-steps ----
        C_COMPUTE(0);
        asm volatile("s_waitcnt lgkmcnt(0)" ::: "memory");
        __builtin_amdgcn_s_barrier();
        STAGE_W2(1);
        asm volatile("s_waitcnt vmcnt(0)" ::: "memory");
        __builtin_amdgcn_s_barrier();
        C_COMPUTE(1);
        asm volatile("s_waitcnt lgkmcnt(0)" ::: "memory");
        __builtin_amdgcn_s_barrier();
    }
#undef STAGE_W2
#undef C_COMPUTE

    // ---- epilogue: out[row] += acc2 + b2 (bounce in R1) ----
    float bv2[3];
    #pragma unroll
    for (int fn = 0; fn < 3; ++fn) bv2[fn] = b2v[wc2 * 48 + fn * 16 + lr];
    float* fb = (float*)R1 + wid * 832;   // 16 x 52 f32 per fm
    #pragma unroll
    for (int fm = 0; fm < 4; ++fm) {
        #pragma unroll
        for (int fn = 0; fn < 3; ++fn)
            #pragma unroll
            for (int r = 0; r < 4; ++r)
                fb[(lg * 4 + r) * 52 + fn * 16 + lr] = acc2[fm][fn][r] + bv2[fn];
        #pragma unroll
        for (int i = 0; i < 3; ++i) {
            int cid = i * 64 + lane;
            int row = cid / 12, c4 = cid - row * 12;
            f32x4 val = *(const f32x4*)&fb[row * 52 + c4 * 4];
            long grow = bm0 + wm * 64 + fm * 16 + row;
            int col = wc2 * 48 + c4 * 4;
            if (grow < M_TOK) {
                float* p = &outf[grow * 192 + col];
                f32x4 old = *(const f32x4*)p;
                *(f32x4*)p = old + val;
            }
        }
    }
}

// ---------------- LDS-free MFMA attention: swapped operands, one wave per (window, head) ----------------
__global__ __launch_bounds__(256) void attn_mfma_kernel(
    const ushort_t* __restrict__ qkv,     // M_PAD x 576 bf16, cols [3][NH][HD], Q pre-scaled
    const float* __restrict__ bm,         // (MLAT, 2, NH, 36, 48) fp32 bias+mask
    ushort_t* __restrict__ av)            // M_PAD x 192 bf16
{
    int wid = threadIdx.x >> 6, lane = threadIdx.x & 63;
    int unit = blockIdx.x * 4 + wid;
    int w = unit / NH, h = unit - (unit / NH) * NH;
    int mlat = w / MLON, mlon = w - mlat * MLON;
    int lr = lane & 15, lg = lane >> 4;

    const ushort_t* Qb = qkv + (long)w * NTOK * 576 + h * HD;
    const ushort_t* Kb = Qb + 192;
    const ushort_t* Vb = Qb + 384;

    bf16x8 kf[3], qf[3];
    #pragma unroll
    for (int t = 0; t < 3; ++t) {
        kf[t] = *(const bf16x8*)&Kb[(long)(t * 16 + lr) * 576 + 8 * lg];
        qf[t] = *(const bf16x8*)&Qb[(long)(t * 16 + lr) * 576 + 8 * lg];
    }
    f32x4 st[3][3] = {};
    #pragma unroll
    for (int mt = 0; mt < 3; ++mt)
        #pragma unroll
        for (int qt = 0; qt < 3; ++qt)
            st[mt][qt] = __builtin_amdgcn_mfma_f32_16x16x32_bf16(kf[mt], qf[qt], st[mt][qt], 0, 0, 0);

    bf16x8 vf[2][2];
    #pragma unroll
    for (int nd = 0; nd < 2; ++nd)
        #pragma unroll
        for (int kt = 0; kt < 2; ++kt)
            #pragma unroll
            for (int j = 0; j < 8; ++j)
                ((short*)&vf[nd][kt])[j] =
                    (short)Vb[(long)(kt * 32 + 8 * lg + j) * 576 + nd * 16 + lr];

    const float* bb = bm + (((mlat * 2 + (mlon == MLON - 1)) * NH) + h) * (36 * 48);

    f32x4 o[2][3] = {};
    int src0 = ((2 * (lg & 1)) << 4) | lr;
    int src1 = src0 + 16;

    #pragma unroll
    for (int qt = 0; qt < 3; ++qt) {
        int qrow = qt * 16 + lr;
        int qq = qrow < 36 ? qrow : 35;
        float v[3][4];
        #pragma unroll
        for (int mt = 0; mt < 3; ++mt) {
            f32x4 b4 = *(const f32x4*)&bb[qq * 48 + mt * 16 + 4 * lg];
            #pragma unroll
            for (int r = 0; r < 4; ++r) v[mt][r] = st[mt][qt][r] + b4[r];
        }
        float mx = v[0][0];
        #pragma unroll
        for (int mt = 0; mt < 3; ++mt)
            #pragma unroll
            for (int r = 0; r < 4; ++r) mx = fmaxf(mx, v[mt][r]);
        mx = fmaxf(mx, __shfl_xor(mx, 16, 64));
        mx = fmaxf(mx, __shfl_xor(mx, 32, 64));
        float p[3][4], sum = 0.f;
        #pragma unroll
        for (int mt = 0; mt < 3; ++mt)
            #pragma unroll
            for (int r = 0; r < 4; ++r) { p[mt][r] = __expf(v[mt][r] - mx); sum += p[mt][r]; }
        sum += __shfl_xor(sum, 16, 64);
        sum += __shfl_xor(sum, 32, 64);
        float rs = 1.0f / sum;

        unsigned int pk[3][2];
        #pragma unroll
        for (int mt = 0; mt < 3; ++mt) {
            pk[mt][0] = cvtpk(p[mt][0] * rs, p[mt][1] * rs);
            pk[mt][1] = cvtpk(p[mt][2] * rs, p[mt][3] * rs);
        }
        unsigned int f0[4], f1[4];
        {
            unsigned int a, b;
            a = (unsigned)__shfl((int)pk[0][0], src0, 64); b = (unsigned)__shfl((int)pk[1][0], src0, 64);
            f0[0] = (lg < 2) ? a : b;
            a = (unsigned)__shfl((int)pk[0][1], src0, 64); b = (unsigned)__shfl((int)pk[1][1], src0, 64);
            f0[1] = (lg < 2) ? a : b;
            a = (unsigned)__shfl((int)pk[0][0], src1, 64); b = (unsigned)__shfl((int)pk[1][0], src1, 64);
            f0[2] = (lg < 2) ? a : b;
            a = (unsigned)__shfl((int)pk[0][1], src1, 64); b = (unsigned)__shfl((int)pk[1][1], src1, 64);
            f0[3] = (lg < 2) ? a : b;
            f1[0] = (lg < 2) ? (unsigned)__shfl((int)pk[2][0], src0, 64) : 0u;
            f1[1] = (lg < 2) ? (unsigned)__shfl((int)pk[2][1], src0, 64) : 0u;
            f1[2] = (lg < 2) ? (unsigned)__shfl((int)pk[2][0], src1, 64) : 0u;
            f1[3] = (lg < 2) ? (unsigned)__shfl((int)pk[2][1], src1, 64) : 0u;
        }
        union { unsigned int u[4]; bf16x8 v8; } pf0, pf1;
        pf0.u[0] = f0[0]; pf0.u[1] = f0[1]; pf0.u[2] = f0[2]; pf0.u[3] = f0[3];
        pf1.u[0] = f1[0]; pf1.u[1] = f1[1]; pf1.u[2] = f1[2]; pf1.u[3] = f1[3];

        #pragma unroll
        for (int nd = 0; nd < 2; ++nd) {
            o[nd][qt] = __builtin_amdgcn_mfma_f32_16x16x32_bf16(vf[nd][0], pf0.v8, o[nd][qt], 0, 0, 0);
            o[nd][qt] = __builtin_amdgcn_mfma_f32_16x16x32_bf16(vf[nd][1], pf1.v8, o[nd][qt], 0, 0, 0);
        }
    }

    #pragma unroll
    for (int qt = 0; qt < 3; ++qt) {
        int qrow = qt * 16 + lr;
        if (qrow < NTOK) {
            #pragma unroll
            for (int nd = 0; nd < 2; ++nd) {
                uint2 pkd;
                pkd.x = cvtpk(o[nd][qt][0], o[nd][qt][1]);
                pkd.y = cvtpk(o[nd][qt][2], o[nd][qt][3]);
                *(uint2*)&av[((long)w * NTOK + qrow) * CC + h * HD + nd * 16 + 4 * lg] = pkd;
            }
        }
    }
}

// ---------------- launch ----------------
extern "C" void kernel_launch(void* const* d_in, const int* in_sizes, int n_in,
                              void* d_out, int out_size, void* d_ws, size_t ws_size,
                              hipStream_t stream) {
    const float* x        = (const float*)d_in[0];
    const float* n1w      = (const float*)d_in[1];
    const float* n1b      = (const float*)d_in[2];
    const float* qkv_w    = (const float*)d_in[3];
    const float* qkv_b    = (const float*)d_in[4];
    const float* proj_w   = (const float*)d_in[5];
    const float* proj_b   = (const float*)d_in[6];
    const float* btab     = (const float*)d_in[7];
    const float* n2w      = (const float*)d_in[8];
    const float* n2b      = (const float*)d_in[9];
    const float* fc1_w    = (const float*)d_in[10];
    const float* fc1_b    = (const float*)d_in[11];
    const float* fc2_w    = (const float*)d_in[12];
    const float* fc2_b    = (const float*)d_in[13];
    float* out = (float*)d_out;

    char* p = (char*)d_ws;
    ushort_t* xw  = (ushort_t*)p;  p += M_PAD * 192 * 2;
    ushort_t* big = (ushort_t*)p;  p += M_PAD * 768 * 2;
    ushort_t* av  = (ushort_t*)p;  p += M_PAD * 192 * 2;
    ushort_t* wqkv = (ushort_t*)p; p += 576 * 192 * 2;
    ushort_t* wproj= (ushort_t*)p; p += 192 * 192 * 2;
    ushort_t* wfc1 = (ushort_t*)p; p += 768 * 192 * 2;
    ushort_t* wfc2 = (ushort_t*)p; p += 192 * 768 * 2;
    float*    bmask= (float*)p;    p += MLAT * 2 * NH * 36 * 48 * 4;

    transpose_all<<<(442368 + 255)/256, 256, 0, stream>>>(
        qkv_w, proj_w, fc1_w, fc2_w, wqkv, wproj, wfc1, wfc2);
    bias_mask_precompute<<<(MLAT*2*NH*36*48 + 255)/256, 256, 0, stream>>>(btab, bmask);
    zero_bf16<<<((int)(M_PAD - M_TOK)*192 + 255)/256, 256, 0, stream>>>(av + M_TOK * 192, (int)(M_PAD - M_TOK) * 192);

    ln1_window_kernel<<<M_PAD / 4, 256, 0, stream>>>(x, n1w, n1b, xw);

    // QKV: (M_PAD x 192) @ (192 x 576), 3 col-blocks (Q block pre-scaled by SCALE_F)
    gemm_bf16<0, 192><<<508 * 3, 512, 0, stream>>>(
        xw, wqkv, qkv_b, big, nullptr, nullptr, nullptr, nullptr, 576, M_PAD, 3, 508 * 3);

    attn_mfma_kernel<<<NWIN * NH / 4, 256, 0, stream>>>(big, bmask, av);

    // proj + window reverse + residual -> out (fp32), fused LN2 -> xw (bf16)
    gemm_bf16<2, 192><<<508, 512, 0, stream>>>(
        av, wproj, proj_b, xw, out, x, n2w, n2b, 192, M_TOK, 1, 508);

    // fused MLP: out += fc2(gelu(fc1(xw)))
    fused_mlp<<<508, 512, 0, stream>>>(xw, wfc1, fc1_b, wfc2, fc2_b, out, 508);
}

// Round 17
// 183.205 us; speedup vs baseline: 1.7970x; 1.2671x over previous
//
#include <hip/hip_runtime.h>
#include <hip/hip_bf16.h>

// ---------------- constants ----------------
constexpr int HH   = 180;
constexpr int WW   = 360;
constexpr int CC   = 192;
constexpr int WS   = 6;
constexpr int SHIFT= 3;
constexpr int NH   = 6;
constexpr int MLAT = HH / WS;   // 30
constexpr int MLON = WW / WS;   // 60
constexpr int NWIN = MLAT * MLON; // 1800
constexpr int NTOK = WS * WS;   // 36
constexpr int HD   = CC / NH;   // 32
constexpr long M_TOK = (long)NWIN * NTOK;  // 64800
constexpr long M_PAD = 65024;              // 508 * 128
constexpr float SCALE_F = 0.17677669529663687f; // 32^-0.5

typedef unsigned short ushort_t;
using bf16x8 = __attribute__((ext_vector_type(8))) short;
using f32x4  = __attribute__((ext_vector_type(4))) float;

static __device__ inline float b2f(ushort_t u) {
    union { float f; unsigned int i; } v; v.i = ((unsigned int)u) << 16; return v.f;
}
static __device__ inline ushort_t f2b(float f) {
    __hip_bfloat16 h = __float2bfloat16(f);   // HW RNE convert
    return *(ushort_t*)&h;
}
static __device__ inline unsigned int cvtpk(float lo, float hi) {
    unsigned int r;
    asm("v_cvt_pk_bf16_f32 %0, %1, %2" : "=v"(r) : "v"(lo), "v"(hi));
    return r;
}

static __device__ inline void gload_lds16(const ushort_t* g, ushort_t* l) {
    __builtin_amdgcn_global_load_lds(
        (const __attribute__((address_space(1))) unsigned int*)g,
        (__attribute__((address_space(3))) unsigned int*)l, 16, 0, 0);
}

// window-order token t -> original flat position (h*W + w)
static __device__ inline int win_map(int ti) {
    int w = ti / NTOK, n = ti - w * NTOK;
    int mlat = w / MLON, mlon = w - mlat * MLON;
    int sh = mlat * WS + n / WS, sw = mlon * WS + (n % WS);
    int hh = sh + SHIFT; if (hh >= HH) hh -= HH;
    int ww2 = sw + SHIFT; if (ww2 >= WW) ww2 -= WW;
    return hh * WW + ww2;
}

// ---------------- merged weight transpose + bf16 convert (one launch) ----------------
__global__ void transpose_all(const float* __restrict__ qkv_w, const float* __restrict__ proj_w,
                              const float* __restrict__ fc1_w, const float* __restrict__ fc2_w,
                              ushort_t* __restrict__ wqkv, ushort_t* __restrict__ wproj,
                              ushort_t* __restrict__ wfc1, ushort_t* __restrict__ wfc2) {
    int e = blockIdx.x * 256 + threadIdx.x;
    const float* in; ushort_t* out; int K, N;
    if (e < 110592)      { in = qkv_w;  out = wqkv;  K = 192; N = 576; }
    else if (e < 147456) { e -= 110592; in = proj_w; out = wproj; K = 192; N = 192; }
    else if (e < 294912) { e -= 147456; in = fc1_w;  out = wfc1;  K = 192; N = 768; }
    else if (e < 442368) { e -= 294912; in = fc2_w;  out = wfc2;  K = 768; N = 192; }
    else return;
    int n = e / K, k = e - n * K;
    out[e] = f2b(in[(long)k * N + n]);
}

__global__ void zero_bf16(ushort_t* __restrict__ p, int count) {
    int e = blockIdx.x * 256 + threadIdx.x;
    if (e < count) p[e] = 0;
}

// ---------------- bias+mask precompute: (MLAT, 2, NH, 36, 48) fp32, pad cols = -1e30 ----------------
static __device__ inline int region1d(int p, int L) {
    return (p < L - WS) ? 0 : ((p < L - SHIFT) ? 1 : 2);
}

__global__ void bias_mask_precompute(const float* __restrict__ bt, float* __restrict__ bm) {
    int idx = blockIdx.x * 256 + threadIdx.x;
    if (idx >= MLAT * 2 * NH * 36 * 48) return;
    int e = idx;
    int j = e % 48; e /= 48;
    int i = e % 36; e /= 36;
    int h = e % NH; e /= NH;
    int lt = e % 2;
    int mlat = e / 2;
    if (j >= 36) { bm[idx] = -1e30f; return; }
    int ih = i / WS, iw = i - ih * WS;
    int jh = j / WS, jw = j - jh * WS;
    int bidx = mlat * 121 + (ih - jh + 5) * 11 + (iw - jw + 5);
    float v = bt[bidx * NH + h];
    int mlon = lt ? (MLON - 1) : 0;
    int ri = region1d(mlat * WS + ih, HH) * 3 + region1d(mlon * WS + iw, WW);
    int rj = region1d(mlat * WS + jh, HH) * 3 + region1d(mlon * WS + jw, WW);
    if (ri != rj) v += -100.0f;
    bm[idx] = v;
}

// ---------------- LN1 + cyclic shift + window partition -> bf16 ----------------
__global__ __launch_bounds__(256) void ln1_window_kernel(
    const float* __restrict__ x, const float* __restrict__ g, const float* __restrict__ b,
    ushort_t* __restrict__ xw)
{
    long t = (long)blockIdx.x * 4 + (threadIdx.x >> 6);
    int lane = threadIdx.x & 63;
    if (t >= M_PAD) return;
    if (t >= M_TOK) {
        ushort_t* o = xw + t * CC;
        o[lane] = 0; o[lane + 64] = 0; o[lane + 128] = 0;
        return;
    }
    int pp = win_map((int)t);
    const float* row = x + (long)pp * CC;
    float v0 = row[lane], v1 = row[lane + 64], v2 = row[lane + 128];
    float s = v0 + v1 + v2;
    float ss = v0 * v0 + v1 * v1 + v2 * v2;
    #pragma unroll
    for (int o = 32; o > 0; o >>= 1) { s += __shfl_xor(s, o, 64); ss += __shfl_xor(ss, o, 64); }
    float mu = s * (1.0f / CC);
    float var = ss * (1.0f / CC) - mu * mu;
    float rinv = rsqrtf(var + 1e-5f);
    ushort_t* o = xw + t * CC;
    o[lane]       = f2b((v0 - mu) * rinv * g[lane]       + b[lane]);
    o[lane + 64]  = f2b((v1 - mu) * rinv * g[lane + 64]  + b[lane + 64]);
    o[lane + 128] = f2b((v2 - mu) * rinv * g[lane + 128] + b[lane + 128]);
}

// ---------------- MFMA GEMM: BM=128, BN=192, BK=64, dbuf, swizzled, 8 waves, C^T fragments ----------------
// Swapped-operand MFMA: acc = mfma(bfr, af, acc) -> lane holds row (tile+lr),
// 4 CONSECUTIVE cols (fn*16+4lg .. +3). Epilogue: cvtpk pairs + wide LDS-bounce writes.
// MODE 0: outb = bf16(acc + bias) [* SCALE for Q cols] (QKV)
// MODE 1: outb = bf16(gelu(acc + bias))                (FC1)
// MODE 2: proj + window-reverse + residual -> outf, AND fused LN2 -> outb (xw)
// MODE 3: outf[row] += acc + bias                      (FC2)
#define BM 128
#define BN 192
#define BK 64

template<int MODE, int KK>
__global__ __launch_bounds__(512, 4) void gemm_bf16(
    const ushort_t* __restrict__ A, const ushort_t* __restrict__ Bt,
    const float* __restrict__ bias,
    ushort_t* __restrict__ outb, float* __restrict__ outf,
    const float* __restrict__ resid,
    const float* __restrict__ g2, const float* __restrict__ b2,
    int N, long Mguard, int ncol, int nwg)
{
    constexpr int nt = KK / BK;              // 3 or 12
    __shared__ __align__(16) ushort_t lds[40960];   // dbuf 2x40960 B

    int tid = threadIdx.x;
    int lane = tid & 63;
    int wid = tid >> 6;
    int lr = lane & 15, lg = lane >> 4;
    int wm = wid >> 2, wn = wid & 3;

    int orig = blockIdx.x;
    int q = nwg >> 3, r8 = nwg & 7;
    int xcd = orig & 7, pos = orig >> 3;
    int wg = (xcd < r8 ? xcd * (q + 1) : r8 * (q + 1) + (xcd - r8) * q) + pos;
    int brow = wg / ncol, bcol = wg - brow * ncol;
    long bm0 = (long)brow * BM;
    int n0 = bcol * BN;

#define STAGE(b, k0) do { \
    char* base = (char*)lds + (b) * 40960; \
    _Pragma("unroll") \
    for (int i = 0; i < 5; ++i) { \
        int abs_b = tid * 16 + i * 8192; \
        int isA = abs_b < 16384; \
        int loc = isA ? abs_b : abs_b - 16384; \
        int row = loc >> 7, cb = loc & 127; \
        int scol = (cb ^ ((row & 7) << 4)) >> 1; \
        const ushort_t* src = isA ? &A[(bm0 + row) * KK + (k0) + scol] \
                                  : &Bt[(long)(n0 + row) * KK + (k0) + scol]; \
        gload_lds16(src, (ushort_t*)(base + abs_b)); \
    } \
} while (0)

    f32x4 acc[4][3] = {};

    STAGE(0, 0);
    asm volatile("s_waitcnt vmcnt(0)" ::: "memory");
    __builtin_amdgcn_s_barrier();

    int xr = (lr & 7) << 4;

    #pragma unroll
    for (int kt = 0; kt < nt; ++kt) {
        if (kt + 1 < nt) {
            STAGE((kt + 1) & 1, (kt + 1) * BK);
            asm volatile("s_waitcnt vmcnt(5)" ::: "memory");
        } else {
            asm volatile("s_waitcnt vmcnt(0)" ::: "memory");
        }
        __builtin_amdgcn_s_barrier();

        const char* base = (const char*)lds + (kt & 1) * 40960;
        __builtin_amdgcn_s_setprio(1);
        #pragma unroll
        for (int s = 0; s < 2; ++s) {
            bf16x8 af[4], bfr[3];
            #pragma unroll
            for (int fm = 0; fm < 4; ++fm) {
                int row = wm * 64 + fm * 16 + lr;
                af[fm] = *(const bf16x8*)(base + row * 128 + ((s * 64 + lg * 16) ^ xr));
            }
            #pragma unroll
            for (int fn = 0; fn < 3; ++fn) {
                int row = wn * 48 + fn * 16 + lr;
                bfr[fn] = *(const bf16x8*)(base + 16384 + row * 128 + ((s * 64 + lg * 16) ^ xr));
            }
            // swapped operands: C^T fragment (lane: 1 row x 4 consecutive cols)
            #pragma unroll
            for (int fm = 0; fm < 4; ++fm)
                #pragma unroll
                for (int fn = 0; fn < 3; ++fn)
                    acc[fm][fn] = __builtin_amdgcn_mfma_f32_16x16x32_bf16(bfr[fn], af[fm], acc[fm][fn], 0, 0, 0);
        }
        __builtin_amdgcn_s_setprio(0);
        asm volatile("s_waitcnt lgkmcnt(0)" ::: "memory");
        __builtin_amdgcn_s_barrier();
    }
#undef STAGE

    // ---- epilogues (staging LDS dead -> reusable). Lane owns row (tile+lr), cols fn*16+4lg..+3 ----
    f32x4 bv4[3];
    #pragma unroll
    for (int fn = 0; fn < 3; ++fn)
        bv4[fn] = *(const f32x4*)&bias[n0 + wn * 48 + fn * 16 + 4 * lg];

    if (MODE == 0 || MODE == 1) {
        ushort_t* bb = lds + wid * 896;   // 16 x 56 bf16 per fm (padded stride)
        #pragma unroll
        for (int fm = 0; fm < 4; ++fm) {
            #pragma unroll
            for (int fn = 0; fn < 3; ++fn) {
                float v[4];
                #pragma unroll
                for (int r = 0; r < 4; ++r) {
                    v[r] = acc[fm][fn][r] + bv4[fn][r];
                    if (MODE == 0) { if (n0 == 0) v[r] *= SCALE_F; }
                    if (MODE == 1) {
                        float e2 = exp2f(v[r] * -2.4556617f);
                        v[r] = v[r] * __builtin_amdgcn_rcpf(1.0f + e2);
                    }
                }
                uint2 pk2 = { cvtpk(v[0], v[1]), cvtpk(v[2], v[3]) };
                *(uint2*)&bb[lr * 56 + fn * 16 + 4 * lg] = pk2;
            }
            asm volatile("s_waitcnt lgkmcnt(0)" ::: "memory");
            #pragma unroll
            for (int i = 0; i < 2; ++i) {
                int cid = i * 64 + lane;
                if (cid < 96) {
                    int row = cid / 6, c6 = cid - row * 6;
                    uint4 val = *(const uint4*)&bb[row * 56 + c6 * 8];
                    long grow = bm0 + wm * 64 + fm * 16 + row;
                    *(uint4*)&outb[grow * (long)N + n0 + wn * 48 + c6 * 8] = val;
                }
            }
        }
    } else if (MODE == 3) {
        float* fb = (float*)lds + wid * 832;   // 16 x 52 f32 per fm (padded stride)
        #pragma unroll
        for (int fm = 0; fm < 4; ++fm) {
            #pragma unroll
            for (int fn = 0; fn < 3; ++fn) {
                f32x4 v = { acc[fm][fn][0] + bv4[fn][0], acc[fm][fn][1] + bv4[fn][1],
                            acc[fm][fn][2] + bv4[fn][2], acc[fm][fn][3] + bv4[fn][3] };
                *(f32x4*)&fb[lr * 52 + fn * 16 + 4 * lg] = v;
            }
            asm volatile("s_waitcnt lgkmcnt(0)" ::: "memory");
            #pragma unroll
            for (int i = 0; i < 3; ++i) {
                int cid = i * 64 + lane;
                int row = cid / 12, c4 = cid - row * 12;
                f32x4 val = *(const f32x4*)&fb[row * 52 + c4 * 4];
                long grow = bm0 + wm * 64 + fm * 16 + row;
                int col = wn * 48 + c4 * 4;
                if (grow < Mguard) {
                    float* p = &outf[grow * 192 + col];
                    f32x4 old = *(const f32x4*)p;
                    *(f32x4*)p = old + val;
                }
            }
        }
    } else { // MODE 2: proj + residual + fused LN2
        float* redS = (float*)((char*)lds + 73728);  // [128][4]
        float* redQ = (float*)((char*)lds + 75776);  // [128][4]
        int*   row_map = (int*)((char*)lds + 78336); // [128]
        if (tid < BM) {
            long t = bm0 + tid;
            row_map[tid] = (t < M_TOK) ? win_map((int)t) : -1;
        }
        asm volatile("s_waitcnt lgkmcnt(0)" ::: "memory");
        __builtin_amdgcn_s_barrier();

        // phase 1: y = acc + bias + resid; per-lane row partials over its 12 cols
        #pragma unroll
        for (int fm = 0; fm < 4; ++fm) {
            int lrow = wm * 64 + fm * 16 + lr;
            int pp = row_map[lrow];
            float s = 0.f, qq = 0.f;
            #pragma unroll
            for (int fn = 0; fn < 3; ++fn) {
                f32x4 rv = {0.f, 0.f, 0.f, 0.f};
                if (pp >= 0) rv = *(const f32x4*)&resid[(long)pp * 192 + wn * 48 + fn * 16 + 4 * lg];
                #pragma unroll
                for (int r = 0; r < 4; ++r) {
                    float vv = acc[fm][fn][r] + bv4[fn][r] + rv[r];
                    acc[fm][fn][r] = vv;
                    s += vv; qq += vv * vv;
                }
            }
            s += __shfl_xor(s, 16, 64);  s += __shfl_xor(s, 32, 64);
            qq += __shfl_xor(qq, 16, 64); qq += __shfl_xor(qq, 32, 64);
            if (lg == 0) { redS[lrow * 4 + wn] = s; redQ[lrow * 4 + wn] = qq; }
        }
        asm volatile("s_waitcnt lgkmcnt(0)" ::: "memory");
        __builtin_amdgcn_s_barrier();

        f32x4 gv4[3], bv24[3];
        #pragma unroll
        for (int fn = 0; fn < 3; ++fn) {
            gv4[fn]  = *(const f32x4*)&g2[wn * 48 + fn * 16 + 4 * lg];
            bv24[fn] = *(const f32x4*)&b2[wn * 48 + fn * 16 + 4 * lg];
        }

        float* fb = (float*)lds + wid * 832;
        ushort_t* bb = (ushort_t*)((char*)lds + 32768) + wid * 896;
        #pragma unroll
        for (int fm = 0; fm < 4; ++fm) {
            int lrow = wm * 64 + fm * 16 + lr;
            float s = redS[lrow * 4 + 0] + redS[lrow * 4 + 1] + redS[lrow * 4 + 2] + redS[lrow * 4 + 3];
            float qq = redQ[lrow * 4 + 0] + redQ[lrow * 4 + 1] + redQ[lrow * 4 + 2] + redQ[lrow * 4 + 3];
            float mu = s * (1.0f / 192.0f);
            float var = qq * (1.0f / 192.0f) - mu * mu;
            float rin = rsqrtf(var + 1e-5f);
            #pragma unroll
            for (int fn = 0; fn < 3; ++fn) {
                *(f32x4*)&fb[lr * 52 + fn * 16 + 4 * lg] = acc[fm][fn];
                float n0v = (acc[fm][fn][0] - mu) * rin * gv4[fn][0] + bv24[fn][0];
                float n1v = (acc[fm][fn][1] - mu) * rin * gv4[fn][1] + bv24[fn][1];
                float n2v = (acc[fm][fn][2] - mu) * rin * gv4[fn][2] + bv24[fn][2];
                float n3v = (acc[fm][fn][3] - mu) * rin * gv4[fn][3] + bv24[fn][3];
                uint2 pk2 = { cvtpk(n0v, n1v), cvtpk(n2v, n3v) };
                *(uint2*)&bb[lr * 56 + fn * 16 + 4 * lg] = pk2;
            }
            asm volatile("s_waitcnt lgkmcnt(0)" ::: "memory");
            #pragma unroll
            for (int i = 0; i < 3; ++i) {
                int cid = i * 64 + lane;
                int row = cid / 12, c4 = cid - row * 12;
                int pp = row_map[wm * 64 + fm * 16 + row];
                if (pp >= 0) {
                    f32x4 val = *(const f32x4*)&fb[row * 52 + c4 * 4];
                    *(f32x4*)&outf[(long)pp * 192 + wn * 48 + c4 * 4] = val;
                }
            }
            #pragma unroll
            for (int i = 0; i < 2; ++i) {
                int cid = i * 64 + lane;
                if (cid < 96) {
                    int row = cid / 6, c6 = cid - row * 6;
                    int pp = row_map[wm * 64 + fm * 16 + row];
                    if (pp >= 0) {
                        uint4 val = *(const uint4*)&bb[row * 56 + c6 * 8];
                        *(uint4*)&outb[(long)pp * 192 + wn * 48 + c6 * 8] = val;
                    }
                }
            }
        }
    }
}

// ---------------- LDS-free MFMA attention: swapped operands, one wave per (window, head) ----------------
__global__ __launch_bounds__(256) void attn_mfma_kernel(
    const ushort_t* __restrict__ qkv,     // M_PAD x 576 bf16, cols [3][NH][HD], Q pre-scaled
    const float* __restrict__ bm,         // (MLAT, 2, NH, 36, 48) fp32 bias+mask
    ushort_t* __restrict__ av)            // M_PAD x 192 bf16
{
    int wid = threadIdx.x >> 6, lane = threadIdx.x & 63;
    int unit = blockIdx.x * 4 + wid;
    int w = unit / NH, h = unit - (unit / NH) * NH;
    int mlat = w / MLON, mlon = w - mlat * MLON;
    int lr = lane & 15, lg = lane >> 4;

    const ushort_t* Qb = qkv + (long)w * NTOK * 576 + h * HD;
    const ushort_t* Kb = Qb + 192;
    const ushort_t* Vb = Qb + 384;

    bf16x8 kf[3], qf[3];
    #pragma unroll
    for (int t = 0; t < 3; ++t) {
        kf[t] = *(const bf16x8*)&Kb[(long)(t * 16 + lr) * 576 + 8 * lg];
        qf[t] = *(const bf16x8*)&Qb[(long)(t * 16 + lr) * 576 + 8 * lg];
    }
    f32x4 st[3][3] = {};
    #pragma unroll
    for (int mt = 0; mt < 3; ++mt)
        #pragma unroll
        for (int qt = 0; qt < 3; ++qt)
            st[mt][qt] = __builtin_amdgcn_mfma_f32_16x16x32_bf16(kf[mt], qf[qt], st[mt][qt], 0, 0, 0);

    bf16x8 vf[2][2];
    #pragma unroll
    for (int nd = 0; nd < 2; ++nd)
        #pragma unroll
        for (int kt = 0; kt < 2; ++kt)
            #pragma unroll
            for (int j = 0; j < 8; ++j)
                ((short*)&vf[nd][kt])[j] =
                    (short)Vb[(long)(kt * 32 + 8 * lg + j) * 576 + nd * 16 + lr];

    const float* bb = bm + (((mlat * 2 + (mlon == MLON - 1)) * NH) + h) * (36 * 48);

    f32x4 o[2][3] = {};
    int src0 = ((2 * (lg & 1)) << 4) | lr;
    int src1 = src0 + 16;

    #pragma unroll
    for (int qt = 0; qt < 3; ++qt) {
        int qrow = qt * 16 + lr;
        int qq = qrow < 36 ? qrow : 35;
        float v[3][4];
        #pragma unroll
        for (int mt = 0; mt < 3; ++mt) {
            f32x4 b4 = *(const f32x4*)&bb[qq * 48 + mt * 16 + 4 * lg];
            #pragma unroll
            for (int r = 0; r < 4; ++r) v[mt][r] = st[mt][qt][r] + b4[r];
        }
        float mx = v[0][0];
        #pragma unroll
        for (int mt = 0; mt < 3; ++mt)
            #pragma unroll
            for (int r = 0; r < 4; ++r) mx = fmaxf(mx, v[mt][r]);
        mx = fmaxf(mx, __shfl_xor(mx, 16, 64));
        mx = fmaxf(mx, __shfl_xor(mx, 32, 64));
        float p[3][4], sum = 0.f;
        #pragma unroll
        for (int mt = 0; mt < 3; ++mt)
            #pragma unroll
            for (int r = 0; r < 4; ++r) { p[mt][r] = __expf(v[mt][r] - mx); sum += p[mt][r]; }
        sum += __shfl_xor(sum, 16, 64);
        sum += __shfl_xor(sum, 32, 64);
        float rs = 1.0f / sum;

        unsigned int pk[3][2];
        #pragma unroll
        for (int mt = 0; mt < 3; ++mt) {
            pk[mt][0] = cvtpk(p[mt][0] * rs, p[mt][1] * rs);
            pk[mt][1] = cvtpk(p[mt][2] * rs, p[mt][3] * rs);
        }
        unsigned int f0[4], f1[4];
        {
            unsigned int a, b;
            a = (unsigned)__shfl((int)pk[0][0], src0, 64); b = (unsigned)__shfl((int)pk[1][0], src0, 64);
            f0[0] = (lg < 2) ? a : b;
            a = (unsigned)__shfl((int)pk[0][1], src0, 64); b = (unsigned)__shfl((int)pk[1][1], src0, 64);
            f0[1] = (lg < 2) ? a : b;
            a = (unsigned)__shfl((int)pk[0][0], src1, 64); b = (unsigned)__shfl((int)pk[1][0], src1, 64);
            f0[2] = (lg < 2) ? a : b;
            a = (unsigned)__shfl((int)pk[0][1], src1, 64); b = (unsigned)__shfl((int)pk[1][1], src1, 64);
            f0[3] = (lg < 2) ? a : b;
            f1[0] = (lg < 2) ? (unsigned)__shfl((int)pk[2][0], src0, 64) : 0u;
            f1[1] = (lg < 2) ? (unsigned)__shfl((int)pk[2][1], src0, 64) : 0u;
            f1[2] = (lg < 2) ? (unsigned)__shfl((int)pk[2][0], src1, 64) : 0u;
            f1[3] = (lg < 2) ? (unsigned)__shfl((int)pk[2][1], src1, 64) : 0u;
        }
        union { unsigned int u[4]; bf16x8 v8; } pf0, pf1;
        pf0.u[0] = f0[0]; pf0.u[1] = f0[1]; pf0.u[2] = f0[2]; pf0.u[3] = f0[3];
        pf1.u[0] = f1[0]; pf1.u[1] = f1[1]; pf1.u[2] = f1[2]; pf1.u[3] = f1[3];

        #pragma unroll
        for (int nd = 0; nd < 2; ++nd) {
            o[nd][qt] = __builtin_amdgcn_mfma_f32_16x16x32_bf16(vf[nd][0], pf0.v8, o[nd][qt], 0, 0, 0);
            o[nd][qt] = __builtin_amdgcn_mfma_f32_16x16x32_bf16(vf[nd][1], pf1.v8, o[nd][qt], 0, 0, 0);
        }
    }

    #pragma unroll
    for (int qt = 0; qt < 3; ++qt) {
        int qrow = qt * 16 + lr;
        if (qrow < NTOK) {
            #pragma unroll
            for (int nd = 0; nd < 2; ++nd) {
                uint2 pkd;
                pkd.x = cvtpk(o[nd][qt][0], o[nd][qt][1]);
                pkd.y = cvtpk(o[nd][qt][2], o[nd][qt][3]);
                *(uint2*)&av[((long)w * NTOK + qrow) * CC + h * HD + nd * 16 + 4 * lg] = pkd;
            }
        }
    }
}

// ---------------- launch ----------------
extern "C" void kernel_launch(void* const* d_in, const int* in_sizes, int n_in,
                              void* d_out, int out_size, void* d_ws, size_t ws_size,
                              hipStream_t stream) {
    const float* x        = (const float*)d_in[0];
    const float* n1w      = (const float*)d_in[1];
    const float* n1b      = (const float*)d_in[2];
    const float* qkv_w    = (const float*)d_in[3];
    const float* qkv_b    = (const float*)d_in[4];
    const float* proj_w   = (const float*)d_in[5];
    const float* proj_b   = (const float*)d_in[6];
    const float* btab     = (const float*)d_in[7];
    const float* n2w      = (const float*)d_in[8];
    const float* n2b      = (const float*)d_in[9];
    const float* fc1_w    = (const float*)d_in[10];
    const float* fc1_b    = (const float*)d_in[11];
    const float* fc2_w    = (const float*)d_in[12];
    const float* fc2_b    = (const float*)d_in[13];
    float* out = (float*)d_out;

    char* p = (char*)d_ws;
    ushort_t* xw  = (ushort_t*)p;  p += M_PAD * 192 * 2;
    ushort_t* big = (ushort_t*)p;  p += M_PAD * 768 * 2;
    ushort_t* av  = (ushort_t*)p;  p += M_PAD * 192 * 2;
    ushort_t* wqkv = (ushort_t*)p; p += 576 * 192 * 2;
    ushort_t* wproj= (ushort_t*)p; p += 192 * 192 * 2;
    ushort_t* wfc1 = (ushort_t*)p; p += 768 * 192 * 2;
    ushort_t* wfc2 = (ushort_t*)p; p += 192 * 768 * 2;
    float*    bmask= (float*)p;    p += MLAT * 2 * NH * 36 * 48 * 4;

    transpose_all<<<(442368 + 255)/256, 256, 0, stream>>>(
        qkv_w, proj_w, fc1_w, fc2_w, wqkv, wproj, wfc1, wfc2);
    bias_mask_precompute<<<(MLAT*2*NH*36*48 + 255)/256, 256, 0, stream>>>(btab, bmask);
    zero_bf16<<<((int)(M_PAD - M_TOK)*192 + 255)/256, 256, 0, stream>>>(av + M_TOK * 192, (int)(M_PAD - M_TOK) * 192);

    ln1_window_kernel<<<M_PAD / 4, 256, 0, stream>>>(x, n1w, n1b, xw);

    // QKV: (M_PAD x 192) @ (192 x 576), 3 col-blocks (Q block pre-scaled by SCALE_F)
    gemm_bf16<0, 192><<<508 * 3, 512, 0, stream>>>(
        xw, wqkv, qkv_b, big, nullptr, nullptr, nullptr, nullptr, 576, M_PAD, 3, 508 * 3);

    attn_mfma_kernel<<<NWIN * NH / 4, 256, 0, stream>>>(big, bmask, av);

    // proj + window reverse + residual -> out (fp32), fused LN2 -> xw (bf16)
    gemm_bf16<2, 192><<<508, 512, 0, stream>>>(
        av, wproj, proj_b, xw, out, x, n2w, n2b, 192, M_TOK, 1, 508);

    // FC1 + GELU: (M_PAD x 192) @ (192 x 768), 4 col-blocks
    gemm_bf16<1, 192><<<508 * 4, 512, 0, stream>>>(
        xw, wfc1, fc1_b, big, nullptr, nullptr, nullptr, nullptr, 768, M_PAD, 4, 508 * 4);

    // FC2 + residual accumulate into out, 1 col-block
    gemm_bf16<3, 768><<<508, 512, 0, stream>>>(
        big, wfc2, fc2_b, nullptr, out, nullptr, nullptr, nullptr, 192, M_TOK, 1, 508);
}